// Round 1
// baseline (11079.150 us; speedup 1.0000x reference)
//
#include <hip/hip_runtime.h>
#include <hip/hip_bf16.h>

#define DXc 256
#define DYc 32
#define Kc 4
#define Hc 128
#define LRf 0.1f
#define REGf 0.01f
#define TSTEPS 1000

// ---------------------------------------------------------------------------
// Setup kernel: derived weight matrices into workspace.
//   Wcat (256x256) = [ e_w1[:256] | P ]  where P = s_xw @ A0,  A0 = tr1w[0:128]
//   W1   (32x256)  = [ Wy | M ]          Wy = e_w1[256:288], M = s_yw @ A1
//   e_w2T(128x128) = e_w2^T
//   WyT  (128x32), MT (128x32)
//   d0   (4x128)   = temb[t]@A2 + th[t]@A3 + s_yb@A1 + s_xb@A0 + tr1b
// ---------------------------------------------------------------------------
__global__ __launch_bounds__(256) void setup_kernel(
    const float* __restrict__ e_w1, const float* __restrict__ s_xw,
    const float* __restrict__ s_yw, const float* __restrict__ s_temb,
    const float* __restrict__ s_t1w, const float* __restrict__ s_t1b,
    const float* __restrict__ s_t2w, const float* __restrict__ s_t2b,
    const float* __restrict__ tr1w, const float* __restrict__ tr1b,
    const float* __restrict__ s_xb, const float* __restrict__ s_yb,
    const float* __restrict__ e_w2,
    float* __restrict__ Wcat, float* __restrict__ W1, float* __restrict__ e_w2T,
    float* __restrict__ WyT, float* __restrict__ MT, float* __restrict__ d0)
{
    const int b = blockIdx.x;
    const int t = threadIdx.x;
    if (b < 64) {
        // P rows 4b..4b+3 and copy of E rows
        #pragma unroll
        for (int i = 0; i < 2; ++i) {
            int idx = t + 256 * i;              // 0..511
            int k = 4 * b + (idx >> 7);
            int c = idx & 127;
            float acc = 0.f;
            for (int h = 0; h < 128; ++h)
                acc += s_xw[k * 128 + h] * tr1w[h * 128 + c];
            Wcat[k * 256 + 128 + c] = acc;
            Wcat[k * 256 + c] = e_w1[k * 128 + c];
        }
    } else if (b == 64) {
        // M = s_yw @ A1
        #pragma unroll
        for (int i = 0; i < 16; ++i) {
            int idx = t + 256 * i;              // 0..4095
            int d = idx >> 7, c = idx & 127;
            float acc = 0.f;
            for (int h = 0; h < 128; ++h)
                acc += s_yw[d * 128 + h] * tr1w[(128 + h) * 128 + c];
            W1[d * 256 + 128 + c] = acc;
            MT[c * 32 + d] = acc;
        }
    } else if (b == 65) {
        // Wy copies
        #pragma unroll
        for (int i = 0; i < 16; ++i) {
            int idx = t + 256 * i;
            int d = idx >> 7, c = idx & 127;
            float v = e_w1[(DXc + d) * 128 + c];
            W1[d * 256 + c] = v;
            WyT[c * 32 + d] = v;
        }
    } else if (b == 66) {
        // e_w2 transpose
        #pragma unroll
        for (int i = 0; i < 64; ++i) {
            int idx = t + 256 * i;
            int h = idx >> 7, c = idx & 127;
            e_w2T[c * 128 + h] = e_w2[h * 128 + c];
        }
    } else {
        // b == 67: th table then d0 table
        __shared__ float thS[4][128];
        #pragma unroll
        for (int i = 0; i < 2; ++i) {
            int idx = t + 256 * i;              // 0..511
            int tt = idx >> 7, c = idx & 127;
            float tau = (float)tt / (float)TSTEPS;
            if (tau < 1e-6f) tau = 1e-6f;
            float acc = s_t2b[c];
            for (int h = 0; h < 128; ++h) {
                float aa = tau * s_t1w[h] + s_t1b[h];
                float s = 1.f / (1.f + expf(-aa));
                acc += aa * s * s_t2w[h * 128 + c];
            }
            thS[tt][c] = acc;
        }
        __syncthreads();
        #pragma unroll
        for (int i = 0; i < 2; ++i) {
            int idx = t + 256 * i;
            int tt = idx >> 7, c = idx & 127;
            float acc = tr1b[c];
            for (int h = 0; h < 128; ++h) {
                acc += s_temb[tt * 128 + h] * tr1w[(256 + h) * 128 + c];
                acc += thS[tt][h]           * tr1w[(384 + h) * 128 + c];
                acc += s_yb[h]              * tr1w[(128 + h) * 128 + c];
                acc += s_xb[h]              * tr1w[h * 128 + c];
            }
            d0[tt * 128 + c] = acc;
        }
    }
}

// ---------------------------------------------------------------------------
// Row precompute: hxe = x@E + e_b1 ; cb = x@P + d0[t]   (one fused GEMM)
// 64 rows/block, 256 threads, thread tile 4 rows x 16 interleaved cols.
// ---------------------------------------------------------------------------
__global__ __launch_bounds__(256) void rowpre_kernel(
    const float* __restrict__ x, const int* __restrict__ tin,
    const float* __restrict__ Wcat, const float* __restrict__ e_b1,
    const float* __restrict__ d0,
    float* __restrict__ hxeP, float* __restrict__ cbP)
{
    __shared__ float XsT[64][68];
    __shared__ int tS[64];
    __shared__ float eb1S[128];

    const int t = threadIdx.x;
    const int r0 = blockIdx.x * 64;
    if (t < 64) { int tv = tin[r0 + t]; tS[t] = tv > 0 ? tv : 0; }
    if (t < 128) eb1S[t] = e_b1[t];

    const int rg = t >> 4;       // 0..15
    const int cg = t & 15;       // 0..15
    const int R = rg << 2;

    float acc[4][16];
    #pragma unroll
    for (int rr = 0; rr < 4; ++rr)
        #pragma unroll
        for (int cc = 0; cc < 16; ++cc) acc[rr][cc] = 0.f;

    for (int kc = 0; kc < 4; ++kc) {
        __syncthreads();
        #pragma unroll
        for (int i = 0; i < 4; ++i) {
            int lin = t + 256 * i;           // 0..1023
            int rr = lin >> 4;               // 0..63
            int c4 = (lin & 15) << 2;        // 0..60
            float4 v = *(const float4*)&x[(size_t)(r0 + rr) * 256 + kc * 64 + c4];
            XsT[c4 + 0][rr] = v.x;
            XsT[c4 + 1][rr] = v.y;
            XsT[c4 + 2][rr] = v.z;
            XsT[c4 + 3][rr] = v.w;
        }
        __syncthreads();
        #pragma unroll 2
        for (int k = 0; k < 64; ++k) {
            float av[4];
            #pragma unroll
            for (int rr = 0; rr < 4; ++rr) av[rr] = XsT[k][R + rr];
            const float* wrow = &Wcat[(size_t)(kc * 64 + k) * 256 + cg];
            #pragma unroll
            for (int cc = 0; cc < 16; ++cc) {
                float bv = wrow[cc * 16];
                #pragma unroll
                for (int rr = 0; rr < 4; ++rr) acc[rr][cc] += av[rr] * bv;
            }
        }
    }
    // epilogue: cols = cg + 16*cc ; cc<8 -> hxe, cc>=8 -> cb
    #pragma unroll
    for (int cc = 0; cc < 8; ++cc) {
        int c = cg + (cc << 4);
        #pragma unroll
        for (int rr = 0; rr < 4; ++rr)
            hxeP[(size_t)(r0 + R + rr) * 128 + c] = acc[rr][cc] + eb1S[c];
    }
    #pragma unroll
    for (int cc = 8; cc < 16; ++cc) {
        int c = cg + ((cc - 8) << 4);
        #pragma unroll
        for (int rr = 0; rr < 4; ++rr)
            cbP[(size_t)(r0 + R + rr) * 128 + c] = acc[rr][cc] + d0[tS[R + rr] * 128 + c];
    }
}

// ---------------------------------------------------------------------------
// Iterate kernel: 32 rows/block, 256 threads, 20 GD steps fully in LDS/regs.
// ---------------------------------------------------------------------------
__global__ __launch_bounds__(256) void iterate_kernel(
    const float* __restrict__ hxeP, const float* __restrict__ cbP,
    const float* __restrict__ W1, const float* __restrict__ e_w2,
    const float* __restrict__ e_w2T, const float* __restrict__ WyT,
    const float* __restrict__ MT, const float* __restrict__ e_w3,
    const float* __restrict__ tr2w, const float* __restrict__ tr2b,
    const float* __restrict__ e_b2, const int* __restrict__ tin,
    const int* __restrict__ stepsPtr, float* __restrict__ yout)
{
    __shared__ float Ys[32][33];     // Ys[d][r] = y[r][d]
    __shared__ float As[128][33];    // h1^T, then dz1^T
    __shared__ float Bs[128][33];    // a^T, then da^T, then dz2^T
    __shared__ float ew3S[512];      // e_w3[h][k] row-major
    __shared__ float tr2wS[512];     // tr2w[h][k] row-major
    __shared__ float eb2S[128];
    __shared__ int   tcS[32];
    __shared__ float vS[32];

    const int t = threadIdx.x;
    const int r0 = blockIdx.x * 32;

    if (t < 32) {
        int tv = tin[r0 + t];
        tcS[t] = tv > 0 ? tv : 0;
        vS[t] = (tv >= 0) ? 1.0f : 0.0f;
    }
    for (int i = t; i < 512; i += 256) { ew3S[i] = e_w3[i]; tr2wS[i] = tr2w[i]; }
    if (t < 128) eb2S[t] = e_b2[t];
    for (int i = t; i < 32 * 33; i += 256) (&Ys[0][0])[i] = 0.0f;
    const int nsteps = stepsPtr[0];

    const int rg = t >> 5;       // 0..7
    const int cg = t & 31;       // 0..31
    const int R = rg << 2;       // 0..28
    const int row = t >> 3;      // 0..31
    const int p = t & 7;         // 0..7
    const int d4 = p << 2;

    const float tb0 = tr2b[0], tb1 = tr2b[1], tb2 = tr2b[2], tb3 = tr2b[3];

    __syncthreads();

    for (int step = 0; step < nsteps; ++step) {
        // ---------- GEMM1: z1 (->h1 into As) and a (into Bs); K=32 ----------
        {
            float acc[4][8];
            #pragma unroll
            for (int rr = 0; rr < 4; ++rr)
                #pragma unroll
                for (int cc = 0; cc < 8; ++cc) acc[rr][cc] = 0.0f;
            #pragma unroll 4
            for (int d = 0; d < 32; ++d) {
                float av[4];
                #pragma unroll
                for (int rr = 0; rr < 4; ++rr) av[rr] = Ys[d][R + rr];
                const float* wrow = &W1[d * 256 + cg];
                #pragma unroll
                for (int cc = 0; cc < 8; ++cc) {
                    float bv = wrow[cc * 32];
                    #pragma unroll
                    for (int rr = 0; rr < 4; ++rr) acc[rr][cc] += av[rr] * bv;
                }
            }
            #pragma unroll
            for (int cc = 0; cc < 4; ++cc) {
                int c = cg + (cc << 5);
                #pragma unroll
                for (int rr = 0; rr < 4; ++rr) {
                    float h = acc[rr][cc] + hxeP[(size_t)(r0 + R + rr) * 128 + c];
                    As[c][R + rr] = h > 0.f ? h : 0.f;
                }
            }
            #pragma unroll
            for (int cc = 4; cc < 8; ++cc) {
                int c = cg + ((cc - 4) << 5);
                #pragma unroll
                for (int rr = 0; rr < 4; ++rr)
                    Bs[c][R + rr] = acc[rr][cc] + cbP[(size_t)(r0 + R + rr) * 128 + c];
            }
        }
        __syncthreads();

        // ---------- pointwise CE: logits, softmax, da (overwrite Bs) ----------
        {
            float lg0 = 0.f, lg1 = 0.f, lg2 = 0.f, lg3 = 0.f;
            const int h0 = p << 4;
            float aval[16], sval[16];
            #pragma unroll
            for (int hh = 0; hh < 16; ++hh) {
                int h = h0 + hh;
                float a = Bs[h][row];
                float s = 1.0f / (1.0f + __expf(-a));
                aval[hh] = a; sval[hh] = s;
                float u = a * s;
                lg0 += u * tr2wS[h * 4 + 0];
                lg1 += u * tr2wS[h * 4 + 1];
                lg2 += u * tr2wS[h * 4 + 2];
                lg3 += u * tr2wS[h * 4 + 3];
            }
            #pragma unroll
            for (int m = 1; m < 8; m <<= 1) {
                lg0 += __shfl_xor(lg0, m);
                lg1 += __shfl_xor(lg1, m);
                lg2 += __shfl_xor(lg2, m);
                lg3 += __shfl_xor(lg3, m);
            }
            lg0 += tb0; lg1 += tb1; lg2 += tb2; lg3 += tb3;
            float mx = fmaxf(fmaxf(lg0, lg1), fmaxf(lg2, lg3));
            float e0 = __expf(lg0 - mx), e1 = __expf(lg1 - mx);
            float e2 = __expf(lg2 - mx), e3 = __expf(lg3 - mx);
            float inv = 1.0f / (e0 + e1 + e2 + e3);
            int tcr = tcS[row];
            float vd = vS[row];
            float dl0 = (e0 * inv - (tcr == 0 ? 1.f : 0.f)) * vd;
            float dl1 = (e1 * inv - (tcr == 1 ? 1.f : 0.f)) * vd;
            float dl2 = (e2 * inv - (tcr == 2 ? 1.f : 0.f)) * vd;
            float dl3 = (e3 * inv - (tcr == 3 ? 1.f : 0.f)) * vd;
            #pragma unroll
            for (int hh = 0; hh < 16; ++hh) {
                int h = h0 + hh;
                float a = aval[hh], s = sval[hh];
                float du = dl0 * tr2wS[h * 4 + 0] + dl1 * tr2wS[h * 4 + 1]
                         + dl2 * tr2wS[h * 4 + 2] + dl3 * tr2wS[h * 4 + 3];
                Bs[h][row] = du * s * (1.0f + a * (1.0f - s));
            }
        }
        __syncthreads();

        // ---------- dy part 1 (CE): dy += da @ M^T ----------
        float g0 = 0.f, g1 = 0.f, g2 = 0.f, g3 = 0.f;
        {
            #pragma unroll 8
            for (int h = 0; h < 128; ++h) {
                float v = Bs[h][row];
                const float4 m4 = *(const float4*)&MT[h * 32 + d4];
                g0 += v * m4.x; g1 += v * m4.y; g2 += v * m4.z; g3 += v * m4.w;
            }
        }
        __syncthreads();

        // ---------- GEMM2: z2 -> dz2 into Bs; K=128 ----------
        {
            float acc[4][4];
            #pragma unroll
            for (int rr = 0; rr < 4; ++rr)
                #pragma unroll
                for (int cc = 0; cc < 4; ++cc) acc[rr][cc] = eb2S[cg + (cc << 5)];
            #pragma unroll 4
            for (int h = 0; h < 128; ++h) {
                float av[4];
                #pragma unroll
                for (int rr = 0; rr < 4; ++rr) av[rr] = As[h][R + rr];
                const float* wrow = &e_w2[h * 128 + cg];
                #pragma unroll
                for (int cc = 0; cc < 4; ++cc) {
                    float bv = wrow[cc << 5];
                    #pragma unroll
                    for (int rr = 0; rr < 4; ++rr) acc[rr][cc] += av[rr] * bv;
                }
            }
            #pragma unroll
            for (int cc = 0; cc < 4; ++cc) {
                int c = cg + (cc << 5);
                #pragma unroll
                for (int rr = 0; rr < 4; ++rr) {
                    float gv = ew3S[c * 4 + tcS[R + rr]];
                    Bs[c][R + rr] = acc[rr][cc] > 0.f ? gv : 0.f;
                }
            }
        }
        __syncthreads();

        // ---------- GEMM_g: dh1 = dz2 @ e_w2^T -> dz1 into As; K=128 ----------
        {
            float acc[4][4];
            #pragma unroll
            for (int rr = 0; rr < 4; ++rr)
                #pragma unroll
                for (int cc = 0; cc < 4; ++cc) acc[rr][cc] = 0.f;
            #pragma unroll 4
            for (int c = 0; c < 128; ++c) {
                float av[4];
                #pragma unroll
                for (int rr = 0; rr < 4; ++rr) av[rr] = Bs[c][R + rr];
                const float* wrow = &e_w2T[c * 128 + cg];
                #pragma unroll
                for (int cc = 0; cc < 4; ++cc) {
                    float bv = wrow[cc << 5];
                    #pragma unroll
                    for (int rr = 0; rr < 4; ++rr) acc[rr][cc] += av[rr] * bv;
                }
            }
            float msk[4][4];
            #pragma unroll
            for (int cc = 0; cc < 4; ++cc) {
                int c = cg + (cc << 5);
                #pragma unroll
                for (int rr = 0; rr < 4; ++rr) msk[rr][cc] = As[c][R + rr];
            }
            __syncthreads();
            #pragma unroll
            for (int cc = 0; cc < 4; ++cc) {
                int c = cg + (cc << 5);
                #pragma unroll
                for (int rr = 0; rr < 4; ++rr)
                    As[c][R + rr] = msk[rr][cc] > 0.f ? acc[rr][cc] : 0.f;
            }
        }
        __syncthreads();

        // ---------- dy part 2 + y update ----------
        {
            #pragma unroll 8
            for (int h = 0; h < 128; ++h) {
                float v = As[h][row];
                const float4 w4 = *(const float4*)&WyT[h * 32 + d4];
                g0 += v * w4.x; g1 += v * w4.y; g2 += v * w4.z; g3 += v * w4.w;
            }
            float y0 = Ys[d4 + 0][row], y1 = Ys[d4 + 1][row];
            float y2 = Ys[d4 + 2][row], y3 = Ys[d4 + 3][row];
            y0 -= LRf * (g0 + 2.f * REGf * y0);
            y1 -= LRf * (g1 + 2.f * REGf * y1);
            y2 -= LRf * (g2 + 2.f * REGf * y2);
            y3 -= LRf * (g3 + 2.f * REGf * y3);
            Ys[d4 + 0][row] = y0;
            Ys[d4 + 1][row] = y1;
            Ys[d4 + 2][row] = y2;
            Ys[d4 + 3][row] = y3;
        }
        __syncthreads();
    }

    // ---------- write out ----------
    {
        float4 o;
        o.x = Ys[d4 + 0][row];
        o.y = Ys[d4 + 1][row];
        o.z = Ys[d4 + 2][row];
        o.w = Ys[d4 + 3][row];
        *(float4*)&yout[(size_t)(r0 + row) * 32 + d4] = o;
    }
}

// ---------------------------------------------------------------------------
extern "C" void kernel_launch(void* const* d_in, const int* in_sizes, int n_in,
                              void* d_out, int out_size, void* d_ws, size_t ws_size,
                              hipStream_t stream)
{
    const float* x      = (const float*)d_in[0];
    const int*   tin    = (const int*)d_in[1];
    const float* e_w1   = (const float*)d_in[2];
    const float* e_b1   = (const float*)d_in[3];
    const float* e_w2   = (const float*)d_in[4];
    const float* e_b2   = (const float*)d_in[5];
    const float* e_w3   = (const float*)d_in[6];
    const float* s_xw   = (const float*)d_in[8];
    const float* s_xb   = (const float*)d_in[9];
    const float* s_yw   = (const float*)d_in[10];
    const float* s_yb   = (const float*)d_in[11];
    const float* s_temb = (const float*)d_in[12];
    const float* s_t1w  = (const float*)d_in[13];
    const float* s_t1b  = (const float*)d_in[14];
    const float* s_t2w  = (const float*)d_in[15];
    const float* s_t2b  = (const float*)d_in[16];
    const float* tr1w   = (const float*)d_in[17];
    const float* tr1b   = (const float*)d_in[18];
    const float* tr2w   = (const float*)d_in[19];
    const float* tr2b   = (const float*)d_in[20];
    const int*   steps  = (const int*)d_in[21];

    const int B = in_sizes[0] / DXc;

    float* ws    = (float*)d_ws;
    float* hxeP  = ws;
    float* cbP   = hxeP + (size_t)B * 128;
    float* Wcat  = cbP  + (size_t)B * 128;
    float* W1    = Wcat + 256 * 256;
    float* e_w2T = W1   + 32 * 256;
    float* WyT   = e_w2T + 128 * 128;
    float* MT    = WyT  + 128 * 32;
    float* d0    = MT   + 128 * 32;

    setup_kernel<<<68, 256, 0, stream>>>(e_w1, s_xw, s_yw, s_temb, s_t1w, s_t1b,
                                         s_t2w, s_t2b, tr1w, tr1b, s_xb, s_yb,
                                         e_w2, Wcat, W1, e_w2T, WyT, MT, d0);
    rowpre_kernel<<<B / 64, 256, 0, stream>>>(x, tin, Wcat, e_b1, d0, hxeP, cbP);
    iterate_kernel<<<B / 32, 256, 0, stream>>>(hxeP, cbP, W1, e_w2, e_w2T, WyT,
                                               MT, e_w3, tr2w, tr2b, e_b2, tin,
                                               steps, (float*)d_out);
}